// Round 4
// baseline (57.127 us; speedup 1.0000x reference)
//
#include <hip/hip_runtime.h>

// out[t] = x[t], except out[t] = 0 when x[t] > 0.5 and (t - lastzero(t)) is even,
// where lastzero(t) = most recent index < t with x <= 0.5 (or -1).
// Derivation: b[t] = (out[t] > thr) obeys b[t] = c[t] && !b[t-1]  (c[t] = x[t] > thr),
// which alternates within runs of c=1 -> parity of distance to last c=0.
//
// Round 3 -> 4: same NT-store plan, but via clang ext_vector_type (the
// builtin rejects HIP_vector_type<float,4>*). NT output stores keep the
// 128 MB input L3-resident (input+output together exactly fill 256 MB L3;
// round-2 counters showed 67 MB/replay HBM re-fetch of x from eviction).

typedef float floatx4 __attribute__((ext_vector_type(4)));

constexpr int S = 8192;
constexpr int TPB = 1024;
constexpr int EPT = S / TPB;  // 8 elements per thread (2 x float4)
constexpr float THR = 0.5f;

__global__ __launch_bounds__(TPB) void notwo_kernel(const float* __restrict__ x,
                                                    float* __restrict__ out) {
    const int row = blockIdx.x;
    const int tid = threadIdx.x;
    const size_t rowoff = (size_t)row * S;

    const floatx4* xv = reinterpret_cast<const floatx4*>(x + rowoff) + tid * 2;
    floatx4 v0 = xv[0];
    floatx4 v1 = xv[1];
    float f[EPT] = {v0.x, v0.y, v0.z, v0.w, v1.x, v1.y, v1.z, v1.w};

    const int base = tid * EPT;

    // Local last-zero index within this thread's chunk (-1 if none).
    int lastz = -1;
    #pragma unroll
    for (int k = 0; k < EPT; ++k) {
        if (!(f[k] > THR)) lastz = base + k;
    }

    // Block-wide exclusive max-scan of lastz (identity -1).
    const int lane = tid & 63;
    const int wv = tid >> 6;  // wave id, 0..15
    int incl = lastz;
    #pragma unroll
    for (int off = 1; off < 64; off <<= 1) {
        // All lanes shuffle unconditionally (ds_bpermute is convergent);
        // lanes < off receive their own value (clamp) so max is a no-op there.
        int up = __shfl_up(incl, off, 64);
        incl = max(incl, up);
    }
    __shared__ int wtot[TPB / 64];
    if (lane == 63) wtot[wv] = incl;
    __syncthreads();
    int prefix = -1;
    #pragma unroll
    for (int w = 0; w < TPB / 64; ++w) {
        int t = wtot[w];
        if (w < wv) prefix = max(prefix, t);
    }
    int up1 = __shfl_up(incl, 1, 64);
    int excl = (lane == 0) ? -1 : up1;
    int carry = max(prefix, excl);  // last zero index strictly before this chunk

    // Walk own 8 elements with the carry.
    #pragma unroll
    for (int k = 0; k < EPT; ++k) {
        const int t = base + k;
        const bool c = f[k] > THR;
        if (c && (((t - carry) & 1) == 0)) f[k] = 0.0f;
        if (!c) carry = t;
    }

    floatx4 o0 = {f[0], f[1], f[2], f[3]};
    floatx4 o1 = {f[4], f[5], f[6], f[7]};
    floatx4* ov = reinterpret_cast<floatx4*>(out + rowoff) + tid * 2;
    __builtin_nontemporal_store(o0, ov);
    __builtin_nontemporal_store(o1, ov + 1);
}

extern "C" void kernel_launch(void* const* d_in, const int* in_sizes, int n_in,
                              void* d_out, int out_size, void* d_ws, size_t ws_size,
                              hipStream_t stream) {
    const float* x = (const float*)d_in[0];
    float* out = (float*)d_out;
    const int B = out_size / S;  // 4096 rows
    notwo_kernel<<<B, TPB, 0, stream>>>(x, out);
}

// Round 5
// 44.274 us; speedup vs baseline: 1.2903x; 1.2903x over previous
//
#include <hip/hip_runtime.h>

// out[t] = x[t], except out[t] = 0 when x[t] > 0.5 and (t - lastzero(t)) is even,
// where lastzero(t) = most recent index < t with x <= 0.5 (or -1).
// b[t] = (out[t] > thr) obeys b[t] = c[t] && !b[t-1]; alternates within c=1 runs
// -> parity of distance to the last c=0 position.
//
// Round 4 -> 5: dense-per-instruction memory layout. Previously lane i touched
// byte i*32 (two adjacent float4s per thread) -> every wave-level load/store
// instruction covered 2 KB at 50% cacheline density (16 lines x 64B). Now each
// wave owns 512 contiguous floats; instruction 0 covers the first 1 KB dense
// (lane*16B), instruction 1 the second. Thread owns two 4-float segments:
//   A: wv*512 + lane*4      B: wv*512 + 256 + lane*4
// Scan: per-segment wave max-scans + A-wave-max broadcast into B's carry.
// NT stores reverted (round 4: +15% WRITE_SIZE from partial-line writeback).

typedef float floatx4 __attribute__((ext_vector_type(4)));

constexpr int S = 8192;
constexpr int TPB = 1024;
constexpr int WAVES = TPB / 64;        // 16
constexpr int WFLOATS = S / WAVES;     // 512 floats per wave
constexpr float THR = 0.5f;

__global__ __launch_bounds__(TPB) void notwo_kernel(const float* __restrict__ x,
                                                    float* __restrict__ out) {
    const int row = blockIdx.x;
    const int tid = threadIdx.x;
    const int lane = tid & 63;
    const int wv = tid >> 6;
    const size_t rowoff = (size_t)row * S;
    const size_t wbase = rowoff + (size_t)wv * WFLOATS;

    const int baseA = wv * WFLOATS + lane * 4;   // in-row index of segment A
    const int baseB = baseA + 256;               // segment B

    floatx4 a = *reinterpret_cast<const floatx4*>(x + wbase + lane * 4);
    floatx4 b = *reinterpret_cast<const floatx4*>(x + wbase + 256 + lane * 4);
    float fa[4] = {a.x, a.y, a.z, a.w};
    float fb[4] = {b.x, b.y, b.z, b.w};

    // Per-segment local last-zero (-1 if none).
    int lzA = -1, lzB = -1;
    #pragma unroll
    for (int k = 0; k < 4; ++k) { if (!(fa[k] > THR)) lzA = baseA + k; }
    #pragma unroll
    for (int k = 0; k < 4; ++k) { if (!(fb[k] > THR)) lzB = baseB + k; }

    // Wave-level inclusive max-scans (all lanes shuffle unconditionally;
    // ds_bpermute is convergent — no divergent guards).
    int inclA = lzA, inclB = lzB;
    #pragma unroll
    for (int off = 1; off < 64; off <<= 1) {
        int uA = __shfl_up(inclA, off, 64);
        int uB = __shfl_up(inclB, off, 64);
        inclA = max(inclA, uA);   // lanes < off get own value (clamp): no-op
        inclB = max(inclB, uB);
    }
    const int waveAmax = __shfl(inclA, 63, 64);  // max over all A in this wave
    const int waveBmax = __shfl(inclB, 63, 64);

    __shared__ int wtot[WAVES];
    if (lane == 0) wtot[wv] = max(waveAmax, waveBmax);
    __syncthreads();
    int prefix = -1;  // last zero strictly before this wave's 512-float region
    #pragma unroll
    for (int w = 0; w < WAVES; ++w) {
        int t = wtot[w];
        if (w < wv) prefix = max(prefix, t);
    }

    int upA = __shfl_up(inclA, 1, 64);
    int upB = __shfl_up(inclB, 1, 64);
    int exclA = (lane == 0) ? -1 : upA;
    int exclB = (lane == 0) ? -1 : upB;
    int carryA = max(prefix, exclA);
    int carryB = max(max(prefix, waveAmax), exclB);  // all A precedes all B

    #pragma unroll
    for (int k = 0; k < 4; ++k) {
        const int t = baseA + k;
        const bool c = fa[k] > THR;
        if (c && (((t - carryA) & 1) == 0)) fa[k] = 0.0f;
        if (!c) carryA = t;
    }
    #pragma unroll
    for (int k = 0; k < 4; ++k) {
        const int t = baseB + k;
        const bool c = fb[k] > THR;
        if (c && (((t - carryB) & 1) == 0)) fb[k] = 0.0f;
        if (!c) carryB = t;
    }

    floatx4 oa = {fa[0], fa[1], fa[2], fa[3]};
    floatx4 ob = {fb[0], fb[1], fb[2], fb[3]};
    *reinterpret_cast<floatx4*>(out + wbase + lane * 4) = oa;
    *reinterpret_cast<floatx4*>(out + wbase + 256 + lane * 4) = ob;
}

extern "C" void kernel_launch(void* const* d_in, const int* in_sizes, int n_in,
                              void* d_out, int out_size, void* d_ws, size_t ws_size,
                              hipStream_t stream) {
    const float* x = (const float*)d_in[0];
    float* out = (float*)d_out;
    const int B = out_size / S;  // 4096 rows
    notwo_kernel<<<B, TPB, 0, stream>>>(x, out);
}